// Round 6
// baseline (641.658 us; speedup 1.0000x reference)
//
#include <hip/hip_runtime.h>
#include <hip/hip_bf16.h>
#include <cstdint>
#include <cstddef>

#define NN 50000
#define NE 600000
#define NG 2000
#define SCAN_TILE 1024
#define NBLK ((NN + SCAN_TILE - 1) / SCAN_TILE)
#define SLOTS 16

// ---------------- CSR build (batched over 2 branches via blockIdx.y) ----------------

__global__ void count2_kernel(const int* __restrict__ d0, const int* __restrict__ d1,
                              int* __restrict__ cnt, int nE) {
    int b = blockIdx.y;
    const int* dst = b ? d1 : d0;
    int e = blockIdx.x * blockDim.x + threadIdx.x;
    if (e < nE) atomicAdd(&cnt[b * NN + dst[e]], 1);
}

__global__ __launch_bounds__(256) void scan_pass1(const int* __restrict__ cnt,
                                                  int* __restrict__ blk, int n) {
    __shared__ int sm[256];
    const int* cb = cnt + blockIdx.y * NN;
    int* bb = blk + blockIdx.y * NBLK;
    int t = threadIdx.x;
    int base = blockIdx.x * SCAN_TILE + t * 4;
    int s = 0;
#pragma unroll
    for (int j = 0; j < 4; ++j) { int i = base + j; if (i < n) s += cb[i]; }
    sm[t] = s;
    __syncthreads();
    for (int off = 128; off > 0; off >>= 1) {
        if (t < off) sm[t] += sm[t + off];
        __syncthreads();
    }
    if (t == 0) bb[blockIdx.x] = sm[0];
}

__global__ __launch_bounds__(256) void scan_pass2(const int* __restrict__ cnt,
                                                  const int* __restrict__ blk,
                                                  int* __restrict__ row_ptr,
                                                  int* __restrict__ cursor, int n) {
    __shared__ int sm[256];
    __shared__ int sbase;
    const int* cb = cnt + blockIdx.y * NN;
    const int* bb = blk + blockIdx.y * NBLK;
    int* rp = row_ptr + blockIdx.y * (NN + 1);
    int* cu = cursor + blockIdx.y * NN;
    int t = threadIdx.x;
    int b = 0;
    for (int i = t; i < blockIdx.x; i += 256) b += bb[i];
    sm[t] = b;
    __syncthreads();
    for (int off = 128; off > 0; off >>= 1) {
        if (t < off) sm[t] += sm[t + off];
        __syncthreads();
    }
    if (t == 0) sbase = sm[0];
    __syncthreads();
    int base = sbase;
    __syncthreads();

    int i0 = blockIdx.x * SCAN_TILE + t * 4;
    int v[4];
    int s = 0;
#pragma unroll
    for (int j = 0; j < 4; ++j) { int i = i0 + j; v[j] = (i < n) ? cb[i] : 0; s += v[j]; }
    sm[t] = s;
    __syncthreads();
    for (int off = 1; off < 256; off <<= 1) {
        int tmp = (t >= off) ? sm[t - off] : 0;
        __syncthreads();
        sm[t] += tmp;
        __syncthreads();
    }
    int run = base + sm[t] - s;
#pragma unroll
    for (int j = 0; j < 4; ++j) {
        int i = i0 + j;
        if (i < n) {
            rp[i] = run;
            cu[i] = run;
            run += v[j];
            if (i == n - 1) rp[n] = run;
        }
    }
}

// packed CSR entry: .x = src index, .y = bit-cast float weight (one 8B store per edge)
__global__ void scatter2_kernel(const int* __restrict__ s0, const int* __restrict__ d0,
                                const int* __restrict__ s1, const int* __restrict__ d1,
                                const int* __restrict__ cnt, int* __restrict__ cursor,
                                int2* __restrict__ perm, int nE) {
    int b = blockIdx.y;
    const int* src = b ? s1 : s0;
    const int* dst = b ? d1 : d0;
    int e = blockIdx.x * blockDim.x + threadIdx.x;
    if (e >= nE) return;
    int d = dst[e];
    int p = atomicAdd(&cursor[b * NN + d], 1);
    int s = src[e];
    float w = rsqrtf((float)cnt[b * NN + s] + 1.0f);
    perm[(size_t)b * NE + p] = make_int2(s, __float_as_int(w));
}

// ---------------- GEMM 1: Y[n,128] = X[n,64] @ W[64,128], wave-per-4-rows ----------------
// W in LDS as interleaved pairs (W[k][j], W[k][j+64]) -> one ds_read_b64 per k per lane.
// x rows staged in wave-private LDS, read back as uniform-address float4 broadcasts.
// STATS: per-lane register accumulation of sum/sumsq, slot-striped atomics at end.
template<bool STATS>
__global__ __launch_bounds__(256) void gemm1_wpr(const float* __restrict__ X0,
                                                 const float* __restrict__ X1,
                                                 const float* __restrict__ W0,
                                                 const float* __restrict__ W1,
                                                 float* __restrict__ Y0,
                                                 float* __restrict__ Y1,
                                                 float* __restrict__ sums, int nRows) {
    __shared__ float Wl[64 * 128];
    __shared__ float Xls[4][4 * 64];
    const int b = blockIdx.y;
    const float* __restrict__ X = b ? X1 : X0;
    const float* __restrict__ W = b ? W1 : W0;
    float* __restrict__ Y = b ? Y1 : Y0;
    const int tid = threadIdx.x;
    const int lane = tid & 63;
    const int w = tid >> 6;

    for (int i = tid; i < 64 * 128; i += 256) {
        float v = W[i];                    // coalesced
        int k = i >> 7, r = i & 127;
        int j = r & 63, h = r >> 6;
        Wl[k * 128 + 2 * j + h] = v;       // 2-way write alias: free
    }
    __syncthreads();

    float st0 = 0.f, st1 = 0.f, sq0 = 0.f, sq1 = 0.f;
    const int wv = blockIdx.x * 4 + w;
    const int sweep = gridDim.x * 16;

    for (int r0 = wv * 4; r0 < nRows; r0 += sweep) {
#pragma unroll
        for (int r = 0; r < 4; ++r) {
            int row = r0 + r;
            float v = (row < nRows) ? X[(size_t)row * 64 + lane] : 0.f;
            Xls[w][r * 64 + lane] = v;     // wave-private: no barrier needed
        }
        float acc[4][2];
#pragma unroll
        for (int r = 0; r < 4; ++r) { acc[r][0] = 0.f; acc[r][1] = 0.f; }
#pragma unroll
        for (int k4 = 0; k4 < 16; ++k4) {
            float4 xr[4];
#pragma unroll
            for (int r = 0; r < 4; ++r)
                xr[r] = *(const float4*)&Xls[w][r * 64 + k4 * 4];  // uniform addr broadcast
#pragma unroll
            for (int kk = 0; kk < 4; ++kk) {
                float2 wp = *(const float2*)&Wl[(k4 * 4 + kk) * 128 + 2 * lane];
#pragma unroll
                for (int r = 0; r < 4; ++r) {
                    float xk = (kk == 0) ? xr[r].x : (kk == 1) ? xr[r].y
                              : (kk == 2) ? xr[r].z : xr[r].w;
                    acc[r][0] = fmaf(xk, wp.x, acc[r][0]);
                    acc[r][1] = fmaf(xk, wp.y, acc[r][1]);
                }
            }
        }
#pragma unroll
        for (int r = 0; r < 4; ++r) {
            int row = r0 + r;
            if (row < nRows) {
                Y[(size_t)row * 128 + lane] = acc[r][0];
                Y[(size_t)row * 128 + 64 + lane] = acc[r][1];
            }
            if (STATS) {   // padded rows have acc==0 exactly: contribute nothing
                st0 += acc[r][0]; sq0 = fmaf(acc[r][0], acc[r][0], sq0);
                st1 += acc[r][1]; sq1 = fmaf(acc[r][1], acc[r][1], sq1);
            }
        }
    }
    if (STATS) {
        int slot = blockIdx.x & (SLOTS - 1);
        float* sb = sums + (size_t)(b * SLOTS + slot) * 256;  // [sum(128) | sumsq(128)]
        atomicAdd(&sb[lane], st0);
        atomicAdd(&sb[64 + lane], st1);
        atomicAdd(&sb[128 + lane], sq0);
        atomicAdd(&sb[192 + lane], sq1);
    }
}

// ---------------- GEMM 2: Y[n,64] = BNReLU(X[n,128]) @ W[128,64], wave-per-4-rows ----------------
__global__ __launch_bounds__(256) void gemm2_wpr(const float* __restrict__ X0,
                                                 const float* __restrict__ X1,
                                                 const float* __restrict__ W0,
                                                 const float* __restrict__ W1,
                                                 const float* __restrict__ scale,
                                                 const float* __restrict__ shift,
                                                 float* __restrict__ Y0,
                                                 float* __restrict__ Y1, int nRows) {
    __shared__ float Wl[128 * 64];
    __shared__ float Xls[4][4 * 128];
    const int b = blockIdx.y;
    const float* __restrict__ X = b ? X1 : X0;
    const float* __restrict__ W = b ? W1 : W0;
    float* __restrict__ Y = b ? Y1 : Y0;
    const int tid = threadIdx.x;
    const int lane = tid & 63;
    const int w = tid >> 6;

    for (int i = tid; i < 128 * 64; i += 256) Wl[i] = W[i];
    __syncthreads();

    const float scL = scale[b * 128 + lane],      shL = shift[b * 128 + lane];
    const float scH = scale[b * 128 + 64 + lane], shH = shift[b * 128 + 64 + lane];

    const int wv = blockIdx.x * 4 + w;
    const int sweep = gridDim.x * 16;

    for (int r0 = wv * 4; r0 < nRows; r0 += sweep) {
#pragma unroll
        for (int r = 0; r < 4; ++r) {
            int row = r0 + r;
            float vlo = 0.f, vhi = 0.f;
            if (row < nRows) {
                vlo = fmaxf(fmaf(X[(size_t)row * 128 + lane], scL, shL), 0.f);
                vhi = fmaxf(fmaf(X[(size_t)row * 128 + 64 + lane], scH, shH), 0.f);
            }
            Xls[w][r * 128 + lane] = vlo;
            Xls[w][r * 128 + 64 + lane] = vhi;
        }
        float acc[4] = {0.f, 0.f, 0.f, 0.f};
#pragma unroll
        for (int k4 = 0; k4 < 32; ++k4) {
            float4 xr[4];
#pragma unroll
            for (int r = 0; r < 4; ++r)
                xr[r] = *(const float4*)&Xls[w][r * 128 + k4 * 4];
#pragma unroll
            for (int kk = 0; kk < 4; ++kk) {
                float wp = Wl[(k4 * 4 + kk) * 64 + lane];
#pragma unroll
                for (int r = 0; r < 4; ++r) {
                    float xk = (kk == 0) ? xr[r].x : (kk == 1) ? xr[r].y
                              : (kk == 2) ? xr[r].z : xr[r].w;
                    acc[r] = fmaf(xk, wp, acc[r]);
                }
            }
        }
#pragma unroll
        for (int r = 0; r < 4; ++r) {
            int row = r0 + r;
            if (row < nRows) Y[(size_t)row * 64 + lane] = acc[r];
        }
    }
}

// ---------------- Batched aggregation (C=64): one wave per dst node, unroll-8 ----------------
template<bool STATS>
__global__ __launch_bounds__(256) void agg2_kernel(const float* __restrict__ h0,
                                                   const float* __restrict__ h1,
                                                   const int* __restrict__ row_ptr,
                                                   const int2* __restrict__ perm,
                                                   const int* __restrict__ cnt,
                                                   float* __restrict__ out,
                                                   float* __restrict__ sums, int nNodes) {
    const int b = blockIdx.y;
    const float* __restrict__ h = b ? h1 : h0;
    const int* rp = row_ptr + b * (NN + 1);
    const int2* pe = perm + (size_t)b * NE;
    const int* cc = cnt + b * NN;
    float* ob = out + (size_t)b * nNodes * 64;

    const int wave = blockIdx.x * 4 + (threadIdx.x >> 6);
    const int lane = threadIdx.x & 63;
    float fin = 0.f;
    const bool active = wave < nNodes;
    if (active) {
        const int d = wave;
        const float di = rsqrtf((float)cc[d] + 1.0f);
        const int p0 = rp[d], p1 = rp[d + 1];
        float a = 0.f;
        for (int p = p0; p < p1; p += 8) {
            int idx[8]; float w[8];
#pragma unroll
            for (int k = 0; k < 8; ++k) {
                bool vld = (p + k) < p1;
                int pk = vld ? (p + k) : p;   // dup of first slot: same cache line, w=0
                int2 en = pe[pk];
                idx[k] = en.x;
                w[k] = vld ? __int_as_float(en.y) : 0.f;
            }
            float v[8];
#pragma unroll
            for (int k = 0; k < 8; ++k) v[k] = h[(size_t)idx[k] * 64 + lane];
#pragma unroll
            for (int k = 0; k < 8; ++k) a = fmaf(w[k], v[k], a);
        }
        float hd = h[(size_t)d * 64 + lane];
        fin = di * fmaf(di, hd, a);   // di*(sum + di*h_d)
        ob[(size_t)d * 64 + lane] = fin;
    }
    if constexpr (STATS) {
        __shared__ float ls[256], ls2[256];
        ls[threadIdx.x] = fin;
        ls2[threadIdx.x] = fin * fin;
        __syncthreads();
        if (threadIdx.x < 64) {
            float s  = ls[threadIdx.x] + ls[threadIdx.x + 64] + ls[threadIdx.x + 128] + ls[threadIdx.x + 192];
            float s2 = ls2[threadIdx.x] + ls2[threadIdx.x + 64] + ls2[threadIdx.x + 128] + ls2[threadIdx.x + 192];
            int slot = blockIdx.x & (SLOTS - 1);
            float* sb = sums + ((size_t)(b * SLOTS + slot) * 2) * 64;
            atomicAdd(&sb[threadIdx.x], s);
            atomicAdd(&sb[64 + threadIdx.x], s2);
        }
    }
}

// ---------------- BN finalize (slot-striped sums) ----------------
__global__ void bn_finalize2_kernel(const float* __restrict__ sums, int C, float invN,
                                    const float* __restrict__ g0, const float* __restrict__ g1,
                                    const float* __restrict__ b0, const float* __restrict__ b1,
                                    float* __restrict__ scale, float* __restrict__ shift) {
    int b = blockIdx.y;
    int c = threadIdx.x;
    if (c >= C) return;
    float s = 0.f, s2 = 0.f;
    for (int k = 0; k < SLOTS; ++k) {
        const float* sb = sums + ((size_t)(b * SLOTS + k) * 2) * C;
        s += sb[c];
        s2 += sb[C + c];
    }
    const float* gamma = b ? g1 : g0;
    const float* beta = b ? b1 : b0;
    float m = s * invN;
    float var = s2 * invN - m * m;
    float sc = gamma[c] * rsqrtf(var + 1e-5f);
    scale[b * C + c] = sc;
    shift[b * C + c] = beta[c] - m * sc;
}

// single (for head)
__global__ void bn_finalize_kernel(const float* __restrict__ sums, int C, float invN,
                                   const float* __restrict__ gamma, const float* __restrict__ beta,
                                   float* __restrict__ scale, float* __restrict__ shift) {
    int c = blockIdx.x * blockDim.x + threadIdx.x;
    if (c >= C) return;
    float m = sums[c] * invN;
    float var = sums[C + c] * invN - m * m;
    float sc = gamma[c] * rsqrtf(var + 1e-5f);
    scale[c] = sc;
    shift[c] = beta[c] - m * sc;
}

// ---------------- Mean pool per graph (batched; batch sorted; binary search) ----------------
__global__ __launch_bounds__(64) void pool2_kernel(const float* __restrict__ x,
                                                   const float* __restrict__ scale,
                                                   const float* __restrict__ shift,
                                                   const int* __restrict__ batch,
                                                   float* __restrict__ Hmean, int n) {
    int b = blockIdx.y;
    const float* xb = x + (size_t)b * NN * 64;
    int g = blockIdx.x;
    int c = threadIdx.x;
    int lo = 0, hi = n;
    while (lo < hi) { int mid = (lo + hi) >> 1; if (batch[mid] < g) lo = mid + 1; else hi = mid; }
    int start = lo;
    hi = n;
    while (lo < hi) { int mid = (lo + hi) >> 1; if (batch[mid] <= g) lo = mid + 1; else hi = mid; }
    int end = lo;
    float s = 0.f;
    float sc = scale[b * 64 + c], sh = shift[b * 64 + c];
    for (int r = start; r < end; ++r)
        s += fmaxf(fmaf(xb[(size_t)r * 64 + c], sc, sh), 0.f);
    float cf = (float)(end - start);
    Hmean[(size_t)g * 128 + b * 64 + c] = s / fmaxf(cf, 1.f);
}

// ---------------- Head ----------------
__global__ __launch_bounds__(64) void head_gemm1_kernel(const float* __restrict__ H,
                                                        const float* __restrict__ Wf1,
                                                        float* __restrict__ T) {
    __shared__ float row[128];
    int g = blockIdx.x;
    int c = threadIdx.x;
    row[c] = H[(size_t)g * 128 + c];
    row[c + 64] = H[(size_t)g * 128 + 64 + c];
    __syncthreads();
    float acc = 0.f;
#pragma unroll 8
    for (int k = 0; k < 128; ++k) acc = fmaf(row[k], Wf1[k * 64 + c], acc);
    T[(size_t)g * 64 + c] = acc;
}

__global__ __launch_bounds__(64) void head_final_kernel(const float* __restrict__ T,
                                                        const float* __restrict__ scale,
                                                        const float* __restrict__ shift,
                                                        const float* __restrict__ Wf2,
                                                        const float* __restrict__ bf2,
                                                        float* __restrict__ out) {
    int g = blockIdx.x;
    int c = threadIdx.x;
    float v = fmaxf(fmaf(T[(size_t)g * 64 + c], scale[c], shift[c]), 0.f) * Wf2[c];
#pragma unroll
    for (int off = 32; off > 0; off >>= 1) v += __shfl_down(v, off, 64);
    if (c == 0) out[g] = v + bf2[0];
}

// single-branch bn_stats for head
template<int C>
__global__ __launch_bounds__(256) void bn_stats_kernel(const float* __restrict__ x, int n,
                                                       float* __restrict__ sums) {
    constexpr int RP = 256 / C;
    __shared__ float ls[256], ls2[256];
    int c = threadIdx.x % C;
    int sub = threadIdx.x / C;
    float s = 0.f, s2 = 0.f;
    for (int r = blockIdx.x * RP + sub; r < n; r += gridDim.x * RP) {
        float v = x[(size_t)r * C + c];
        s += v; s2 += v * v;
    }
    ls[threadIdx.x] = s; ls2[threadIdx.x] = s2;
    __syncthreads();
    if (sub == 0) {
#pragma unroll
        for (int k = 1; k < RP; ++k) { s += ls[k * C + c]; s2 += ls2[k * C + c]; }
        atomicAdd(&sums[c], s);
        atomicAdd(&sums[C + c], s2);
    }
}

// ---------------- Host orchestration ----------------

static inline size_t alignup(size_t x) { return (x + 255) & ~(size_t)255; }

extern "C" void kernel_launch(void* const* d_in, const int* in_sizes, int n_in,
                              void* d_out, int out_size, void* d_ws, size_t ws_size,
                              hipStream_t stream) {
    const float* xc  = (const float*)d_in[0];
    const float* xs  = (const float*)d_in[1];
    const int*   eic = (const int*)d_in[2];
    const int*   eis = (const int*)d_in[3];
    const int*   batch = (const int*)d_in[4];
    const float* W1c = (const float*)d_in[5];
    const float* g1c = (const float*)d_in[7];
    const float* be1c = (const float*)d_in[8];
    const float* W2c = (const float*)d_in[9];
    const float* g2c = (const float*)d_in[11];
    const float* be2c = (const float*)d_in[12];
    const float* W1s = (const float*)d_in[13];
    const float* g1s = (const float*)d_in[15];
    const float* be1s = (const float*)d_in[16];
    const float* W2s = (const float*)d_in[17];
    const float* g2s = (const float*)d_in[19];
    const float* be2s = (const float*)d_in[20];
    const float* Wf1 = (const float*)d_in[21];
    const float* gf1 = (const float*)d_in[23];
    const float* bef1 = (const float*)d_in[24];
    const float* Wf2 = (const float*)d_in[25];
    const float* bf2 = (const float*)d_in[26];
    float* out = (float*)d_out;

    char* ws = (char*)d_ws;
    size_t off = 0;
    auto alloc = [&](size_t bytes) { char* p = ws + off; off += alignup(bytes); return p; };

    int*   cnt      = (int*)alloc(2 * NN * 4);
    int*   row_ptr  = (int*)alloc(2 * (NN + 1) * 4);
    int*   cursor   = (int*)alloc(2 * NN * 4);
    int*   blk      = (int*)alloc(2 * NBLK * 4);
    int2*  perm     = (int2*)alloc(((size_t)2 * NE + 64) * 8);
    float* aggx     = (float*)alloc((size_t)2 * NN * 64 * 4);
    float* h1buf    = (float*)alloc((size_t)2 * NN * 128 * 4);
    float* h2buf    = (float*)alloc((size_t)2 * NN * 64 * 4);
    float* sums     = (float*)alloc((size_t)2 * SLOTS * 2 * 128 * 4);  // 32 KB
    float* hsums    = (float*)alloc(128 * 4);
    float* bnscale  = (float*)alloc(2 * 128 * 4);
    float* bnshift  = (float*)alloc(2 * 128 * 4);
    float* Hmean    = (float*)alloc((size_t)NG * 128 * 4);
    float* T        = (float*)alloc((size_t)NG * 64 * 4);

    const float invN = 1.0f / (float)NN;
    const dim3 eg((NE + 255) / 256, 2);
    const size_t sumsBytes = (size_t)2 * SLOTS * 2 * 128 * 4;

    // ---- CSR build for both branches ----
    hipMemsetAsync(cnt, 0, 2 * NN * 4, stream);
    count2_kernel<<<eg, 256, 0, stream>>>(eic + NE, eis + NE, cnt, NE);
    scan_pass1<<<dim3(NBLK, 2), 256, 0, stream>>>(cnt, blk, NN);
    scan_pass2<<<dim3(NBLK, 2), 256, 0, stream>>>(cnt, blk, row_ptr, cursor, NN);
    scatter2_kernel<<<eg, 256, 0, stream>>>(eic, eic + NE, eis, eis + NE,
                                            cnt, cursor, perm, NE);

    // ---- Layer 1: aggregate raw x (64ch), then GEMM 64->128 with fused BN stats ----
    agg2_kernel<false><<<dim3((NN + 3) / 4, 2), 256, 0, stream>>>(
        xc, xs, row_ptr, perm, cnt, aggx, nullptr, NN);
    hipMemsetAsync(sums, 0, sumsBytes, stream);
    gemm1_wpr<true><<<dim3(391, 2), 256, 0, stream>>>(
        aggx, aggx + (size_t)NN * 64, W1c, W1s,
        h1buf, h1buf + (size_t)NN * 128, sums, NN);
    bn_finalize2_kernel<<<dim3(1, 2), 128, 0, stream>>>(sums, 128, invN,
                                                        g1c, g1s, be1c, be1s, bnscale, bnshift);

    // ---- Layer 2: BN+ReLU fused into GEMM load, 128->64, then aggregate w/ fused stats ----
    gemm2_wpr<<<dim3(391, 2), 256, 0, stream>>>(
        h1buf, h1buf + (size_t)NN * 128, W2c, W2s, bnscale, bnshift,
        h2buf, h2buf + (size_t)NN * 64, NN);
    hipMemsetAsync(sums, 0, sumsBytes, stream);
    agg2_kernel<true><<<dim3((NN + 3) / 4, 2), 256, 0, stream>>>(
        h2buf, h2buf + (size_t)NN * 64, row_ptr, perm, cnt, aggx, sums, NN);
    bn_finalize2_kernel<<<dim3(1, 2), 64, 0, stream>>>(sums, 64, invN,
                                                       g2c, g2s, be2c, be2s, bnscale, bnshift);

    // ---- Pool (BN+ReLU fused) ----
    pool2_kernel<<<dim3(NG, 2), 64, 0, stream>>>(aggx, bnscale, bnshift, batch, Hmean, NN);

    // ---- Head ----
    head_gemm1_kernel<<<NG, 64, 0, stream>>>(Hmean, Wf1, T);
    hipMemsetAsync(hsums, 0, 128 * 4, stream);
    bn_stats_kernel<64><<<32, 256, 0, stream>>>(T, NG, hsums);
    bn_finalize_kernel<<<1, 64, 0, stream>>>(hsums, 64, 1.0f / (float)NG, gf1, bef1,
                                             bnscale, bnshift);
    head_final_kernel<<<NG, 64, 0, stream>>>(T, bnscale, bnshift, Wf2, bf2, out);
}

// Round 7
// 521.713 us; speedup vs baseline: 1.2299x; 1.2299x over previous
//
#include <hip/hip_runtime.h>
#include <hip/hip_bf16.h>
#include <cstdint>
#include <cstddef>

#define NN 50000
#define NE 600000
#define NG 2000
#define SCAN_TILE 1024
#define NBLK ((NN + SCAN_TILE - 1) / SCAN_TILE)
#define SLOTS 16

// ---------------- CSR build (batched over 2 branches via blockIdx.y) ----------------

__global__ void count2_kernel(const int* __restrict__ d0, const int* __restrict__ d1,
                              int* __restrict__ cnt, int nE) {
    int b = blockIdx.y;
    const int* dst = b ? d1 : d0;
    int e = blockIdx.x * blockDim.x + threadIdx.x;
    if (e < nE) atomicAdd(&cnt[b * NN + dst[e]], 1);
}

__global__ __launch_bounds__(256) void scan_pass1(const int* __restrict__ cnt,
                                                  int* __restrict__ blk, int n) {
    __shared__ int sm[256];
    const int* cb = cnt + blockIdx.y * NN;
    int* bb = blk + blockIdx.y * NBLK;
    int t = threadIdx.x;
    int base = blockIdx.x * SCAN_TILE + t * 4;
    int s = 0;
#pragma unroll
    for (int j = 0; j < 4; ++j) { int i = base + j; if (i < n) s += cb[i]; }
    sm[t] = s;
    __syncthreads();
    for (int off = 128; off > 0; off >>= 1) {
        if (t < off) sm[t] += sm[t + off];
        __syncthreads();
    }
    if (t == 0) bb[blockIdx.x] = sm[0];
}

__global__ __launch_bounds__(256) void scan_pass2(const int* __restrict__ cnt,
                                                  const int* __restrict__ blk,
                                                  int* __restrict__ row_ptr,
                                                  int* __restrict__ cursor, int n) {
    __shared__ int sm[256];
    __shared__ int sbase;
    const int* cb = cnt + blockIdx.y * NN;
    const int* bb = blk + blockIdx.y * NBLK;
    int* rp = row_ptr + blockIdx.y * (NN + 1);
    int* cu = cursor + blockIdx.y * NN;
    int t = threadIdx.x;
    int b = 0;
    for (int i = t; i < blockIdx.x; i += 256) b += bb[i];
    sm[t] = b;
    __syncthreads();
    for (int off = 128; off > 0; off >>= 1) {
        if (t < off) sm[t] += sm[t + off];
        __syncthreads();
    }
    if (t == 0) sbase = sm[0];
    __syncthreads();
    int base = sbase;
    __syncthreads();

    int i0 = blockIdx.x * SCAN_TILE + t * 4;
    int v[4];
    int s = 0;
#pragma unroll
    for (int j = 0; j < 4; ++j) { int i = i0 + j; v[j] = (i < n) ? cb[i] : 0; s += v[j]; }
    sm[t] = s;
    __syncthreads();
    for (int off = 1; off < 256; off <<= 1) {
        int tmp = (t >= off) ? sm[t - off] : 0;
        __syncthreads();
        sm[t] += tmp;
        __syncthreads();
    }
    int run = base + sm[t] - s;
#pragma unroll
    for (int j = 0; j < 4; ++j) {
        int i = i0 + j;
        if (i < n) {
            rp[i] = run;
            cu[i] = run;
            run += v[j];
            if (i == n - 1) rp[n] = run;
        }
    }
}

// packed CSR entry: .x = src index, .y = bit-cast float weight (one 8B store per edge)
__global__ void scatter2_kernel(const int* __restrict__ s0, const int* __restrict__ d0,
                                const int* __restrict__ s1, const int* __restrict__ d1,
                                const int* __restrict__ cnt, int* __restrict__ cursor,
                                int2* __restrict__ perm, int nE) {
    int b = blockIdx.y;
    const int* src = b ? s1 : s0;
    const int* dst = b ? d1 : d0;
    int e = blockIdx.x * blockDim.x + threadIdx.x;
    if (e >= nE) return;
    int d = dst[e];
    int p = atomicAdd(&cursor[b * NN + d], 1);
    int s = src[e];
    float w = rsqrtf((float)cnt[b * NN + s] + 1.0f);
    perm[(size_t)b * NE + p] = make_int2(s, __float_as_int(w));
}

// ---------------- GEMM1: Y[n,128] = X[n,64] @ W[64,128], 64-row tile ----------------
// thread = 8 rows x 4 cols. Ws float4 reads conflict-free; Xs [k][row] pad-68,
// a-vector = 2 aligned broadcast ds_read_b128. Stats fused (LDS reduce + slot atomics).
template<bool STATS>
__global__ __launch_bounds__(256) void gemm1_tile(const float* __restrict__ X0,
                                                  const float* __restrict__ X1,
                                                  const float* __restrict__ W0,
                                                  const float* __restrict__ W1,
                                                  float* __restrict__ Y0,
                                                  float* __restrict__ Y1,
                                                  float* __restrict__ sums, int nRows) {
    __shared__ float Ws[64 * 128];   // 32 KB
    __shared__ float Xs[64 * 68];    // 17.4 KB, [k][row], pad 68 (16B-aligned rows of 8)
    __shared__ float ls[128], ls2[128];
    const int b = blockIdx.y;
    const float* __restrict__ X = b ? X1 : X0;
    const float* __restrict__ W = b ? W1 : W0;
    float* __restrict__ Y = b ? Y1 : Y0;
    const int tid = threadIdx.x;
    const int row0 = blockIdx.x * 64;

    for (int i = tid; i < 64 * 128; i += 256) Ws[i] = W[i];
    for (int i = tid; i < 64 * 64; i += 256) {
        int row = i >> 6, k = i & 63;
        int gr = row0 + row;
        Xs[k * 68 + row] = (gr < nRows) ? X[(size_t)gr * 64 + k] : 0.f;
    }
    if (STATS) {
        for (int i = tid; i < 128; i += 256) { ls[i] = 0.f; ls2[i] = 0.f; }
    }
    __syncthreads();

    const int cg = tid & 31;   // 32 col-groups x 4 cols
    const int rg = tid >> 5;   // 8 row-groups x 8 rows
    float acc[8][4];
#pragma unroll
    for (int r = 0; r < 8; ++r)
#pragma unroll
        for (int j = 0; j < 4; ++j) acc[r][j] = 0.f;

#pragma unroll 4
    for (int k = 0; k < 64; ++k) {
        float4 b4 = *(const float4*)&Ws[k * 128 + cg * 4];
        float4 a0 = *(const float4*)&Xs[k * 68 + rg * 8];
        float4 a1 = *(const float4*)&Xs[k * 68 + rg * 8 + 4];
        float a[8] = {a0.x, a0.y, a0.z, a0.w, a1.x, a1.y, a1.z, a1.w};
#pragma unroll
        for (int r = 0; r < 8; ++r) {
            acc[r][0] = fmaf(a[r], b4.x, acc[r][0]);
            acc[r][1] = fmaf(a[r], b4.y, acc[r][1]);
            acc[r][2] = fmaf(a[r], b4.z, acc[r][2]);
            acc[r][3] = fmaf(a[r], b4.w, acc[r][3]);
        }
    }
#pragma unroll
    for (int r = 0; r < 8; ++r) {
        int gr = row0 + rg * 8 + r;
        if (gr < nRows) {
            float4 st = make_float4(acc[r][0], acc[r][1], acc[r][2], acc[r][3]);
            *(float4*)&Y[(size_t)gr * 128 + cg * 4] = st;
        }
    }
    if (STATS) {   // pad rows have acc==0 exactly: contribute nothing
#pragma unroll
        for (int j = 0; j < 4; ++j) {
            float sj = 0.f, s2j = 0.f;
#pragma unroll
            for (int r = 0; r < 8; ++r) { float v = acc[r][j]; sj += v; s2j = fmaf(v, v, s2j); }
            atomicAdd(&ls[cg * 4 + j], sj);
            atomicAdd(&ls2[cg * 4 + j], s2j);
        }
        __syncthreads();
        int slot = blockIdx.x & (SLOTS - 1);
        float* sb = sums + (size_t)(b * SLOTS + slot) * 256;  // [sum(128)|sumsq(128)]
        if (tid < 128) {
            atomicAdd(&sb[tid], ls[tid]);
            atomicAdd(&sb[128 + tid], ls2[tid]);
        }
    }
}

// ---------------- GEMM2: Y[n,64] = BNReLU(X[n,128]) @ W[128,64], 64x64 tile, K-chunked ----------------
__global__ __launch_bounds__(256) void gemm2_tile(const float* __restrict__ X0,
                                                  const float* __restrict__ X1,
                                                  const float* __restrict__ W0,
                                                  const float* __restrict__ W1,
                                                  const float* __restrict__ scale,
                                                  const float* __restrict__ shift,
                                                  float* __restrict__ Y0,
                                                  float* __restrict__ Y1, int nRows) {
    __shared__ float Ws[128 * 64];   // 32 KB
    __shared__ float Xs[64 * 68];    // 17.4 KB chunk: [kk][row]
    const int b = blockIdx.y;
    const float* __restrict__ X = b ? X1 : X0;
    const float* __restrict__ W = b ? W1 : W0;
    const float* sc = scale + b * 128;
    const float* sh = shift + b * 128;
    float* __restrict__ Y = b ? Y1 : Y0;
    const int tid = threadIdx.x;
    const int row0 = blockIdx.x * 64;

    for (int i = tid; i < 128 * 64; i += 256) Ws[i] = W[i];

    const int cg = tid & 15;   // 16 col-groups x 4 cols
    const int rg = tid >> 4;   // 16 row-groups x 4 rows
    float acc[4][4];
#pragma unroll
    for (int r = 0; r < 4; ++r)
#pragma unroll
        for (int j = 0; j < 4; ++j) acc[r][j] = 0.f;

    for (int ch = 0; ch < 2; ++ch) {
        __syncthreads();   // Ws ready (ch=0) / previous-chunk reads done (ch=1)
        for (int i = tid; i < 64 * 64; i += 256) {
            int row = i >> 6, kk = i & 63;
            int kg = ch * 64 + kk;
            int gr = row0 + row;
            float v = 0.f;
            if (gr < nRows) v = fmaxf(fmaf(X[(size_t)gr * 128 + kg], sc[kg], sh[kg]), 0.f);
            Xs[kk * 68 + row] = v;
        }
        __syncthreads();
#pragma unroll 4
        for (int kk = 0; kk < 64; ++kk) {
            float4 b4 = *(const float4*)&Ws[(ch * 64 + kk) * 64 + cg * 4];
            float4 a4 = *(const float4*)&Xs[kk * 68 + rg * 4];
            float a[4] = {a4.x, a4.y, a4.z, a4.w};
#pragma unroll
            for (int r = 0; r < 4; ++r) {
                acc[r][0] = fmaf(a[r], b4.x, acc[r][0]);
                acc[r][1] = fmaf(a[r], b4.y, acc[r][1]);
                acc[r][2] = fmaf(a[r], b4.z, acc[r][2]);
                acc[r][3] = fmaf(a[r], b4.w, acc[r][3]);
            }
        }
    }
#pragma unroll
    for (int r = 0; r < 4; ++r) {
        int gr = row0 + rg * 4 + r;
        if (gr < nRows) {
            float4 st = make_float4(acc[r][0], acc[r][1], acc[r][2], acc[r][3]);
            *(float4*)&Y[(size_t)gr * 64 + cg * 4] = st;
        }
    }
}

// ---------------- Batched aggregation (C=64): one wave per dst node, unroll-8 ----------------
template<bool STATS>
__global__ __launch_bounds__(256) void agg2_kernel(const float* __restrict__ h0,
                                                   const float* __restrict__ h1,
                                                   const int* __restrict__ row_ptr,
                                                   const int2* __restrict__ perm,
                                                   const int* __restrict__ cnt,
                                                   float* __restrict__ out,
                                                   float* __restrict__ sums, int nNodes) {
    const int b = blockIdx.y;
    const float* __restrict__ h = b ? h1 : h0;
    const int* rp = row_ptr + b * (NN + 1);
    const int2* pe = perm + (size_t)b * NE;
    const int* cc = cnt + b * NN;
    float* ob = out + (size_t)b * nNodes * 64;

    const int wave = blockIdx.x * 4 + (threadIdx.x >> 6);
    const int lane = threadIdx.x & 63;
    float fin = 0.f;
    const bool active = wave < nNodes;
    if (active) {
        const int d = wave;
        const float di = rsqrtf((float)cc[d] + 1.0f);
        const int p0 = rp[d], p1 = rp[d + 1];
        float a = 0.f;
        for (int p = p0; p < p1; p += 8) {
            int idx[8]; float w[8];
#pragma unroll
            for (int k = 0; k < 8; ++k) {
                bool vld = (p + k) < p1;
                int pk = vld ? (p + k) : p;   // dup of first slot: same cache line, w=0
                int2 en = pe[pk];
                idx[k] = en.x;
                w[k] = vld ? __int_as_float(en.y) : 0.f;
            }
            float v[8];
#pragma unroll
            for (int k = 0; k < 8; ++k) v[k] = h[(size_t)idx[k] * 64 + lane];
#pragma unroll
            for (int k = 0; k < 8; ++k) a = fmaf(w[k], v[k], a);
        }
        float hd = h[(size_t)d * 64 + lane];
        fin = di * fmaf(di, hd, a);   // di*(sum + di*h_d)
        ob[(size_t)d * 64 + lane] = fin;
    }
    if constexpr (STATS) {
        __shared__ float ls[256], ls2[256];
        ls[threadIdx.x] = fin;
        ls2[threadIdx.x] = fin * fin;
        __syncthreads();
        if (threadIdx.x < 64) {
            float s  = ls[threadIdx.x] + ls[threadIdx.x + 64] + ls[threadIdx.x + 128] + ls[threadIdx.x + 192];
            float s2 = ls2[threadIdx.x] + ls2[threadIdx.x + 64] + ls2[threadIdx.x + 128] + ls2[threadIdx.x + 192];
            int slot = blockIdx.x & (SLOTS - 1);
            float* sb = sums + ((size_t)(b * SLOTS + slot) * 2) * 64;
            atomicAdd(&sb[threadIdx.x], s);
            atomicAdd(&sb[64 + threadIdx.x], s2);
        }
    }
}

// ---------------- BN finalize (slot-striped sums) ----------------
__global__ void bn_finalize2_kernel(const float* __restrict__ sums, int C, float invN,
                                    const float* __restrict__ g0, const float* __restrict__ g1,
                                    const float* __restrict__ b0, const float* __restrict__ b1,
                                    float* __restrict__ scale, float* __restrict__ shift) {
    int b = blockIdx.y;
    int c = threadIdx.x;
    if (c >= C) return;
    float s = 0.f, s2 = 0.f;
    for (int k = 0; k < SLOTS; ++k) {
        const float* sb = sums + ((size_t)(b * SLOTS + k) * 2) * C;
        s += sb[c];
        s2 += sb[C + c];
    }
    const float* gamma = b ? g1 : g0;
    const float* beta = b ? b1 : b0;
    float m = s * invN;
    float var = s2 * invN - m * m;
    float sc = gamma[c] * rsqrtf(var + 1e-5f);
    scale[b * C + c] = sc;
    shift[b * C + c] = beta[c] - m * sc;
}

// single (for head)
__global__ void bn_finalize_kernel(const float* __restrict__ sums, int C, float invN,
                                   const float* __restrict__ gamma, const float* __restrict__ beta,
                                   float* __restrict__ scale, float* __restrict__ shift) {
    int c = blockIdx.x * blockDim.x + threadIdx.x;
    if (c >= C) return;
    float m = sums[c] * invN;
    float var = sums[C + c] * invN - m * m;
    float sc = gamma[c] * rsqrtf(var + 1e-5f);
    scale[c] = sc;
    shift[c] = beta[c] - m * sc;
}

// ---------------- Mean pool per graph (batched; batch sorted; binary search) ----------------
__global__ __launch_bounds__(64) void pool2_kernel(const float* __restrict__ x,
                                                   const float* __restrict__ scale,
                                                   const float* __restrict__ shift,
                                                   const int* __restrict__ batch,
                                                   float* __restrict__ Hmean, int n) {
    int b = blockIdx.y;
    const float* xb = x + (size_t)b * NN * 64;
    int g = blockIdx.x;
    int c = threadIdx.x;
    int lo = 0, hi = n;
    while (lo < hi) { int mid = (lo + hi) >> 1; if (batch[mid] < g) lo = mid + 1; else hi = mid; }
    int start = lo;
    hi = n;
    while (lo < hi) { int mid = (lo + hi) >> 1; if (batch[mid] <= g) lo = mid + 1; else hi = mid; }
    int end = lo;
    float s = 0.f;
    float sc = scale[b * 64 + c], sh = shift[b * 64 + c];
    for (int r = start; r < end; ++r)
        s += fmaxf(fmaf(xb[(size_t)r * 64 + c], sc, sh), 0.f);
    float cf = (float)(end - start);
    Hmean[(size_t)g * 128 + b * 64 + c] = s / fmaxf(cf, 1.f);
}

// ---------------- Head ----------------
__global__ __launch_bounds__(64) void head_gemm1_kernel(const float* __restrict__ H,
                                                        const float* __restrict__ Wf1,
                                                        float* __restrict__ T) {
    __shared__ float row[128];
    int g = blockIdx.x;
    int c = threadIdx.x;
    row[c] = H[(size_t)g * 128 + c];
    row[c + 64] = H[(size_t)g * 128 + 64 + c];
    __syncthreads();
    float acc = 0.f;
#pragma unroll 8
    for (int k = 0; k < 128; ++k) acc = fmaf(row[k], Wf1[k * 64 + c], acc);
    T[(size_t)g * 64 + c] = acc;
}

__global__ __launch_bounds__(64) void head_final_kernel(const float* __restrict__ T,
                                                        const float* __restrict__ scale,
                                                        const float* __restrict__ shift,
                                                        const float* __restrict__ Wf2,
                                                        const float* __restrict__ bf2,
                                                        float* __restrict__ out) {
    int g = blockIdx.x;
    int c = threadIdx.x;
    float v = fmaxf(fmaf(T[(size_t)g * 64 + c], scale[c], shift[c]), 0.f) * Wf2[c];
#pragma unroll
    for (int off = 32; off > 0; off >>= 1) v += __shfl_down(v, off, 64);
    if (c == 0) out[g] = v + bf2[0];
}

// single-branch bn_stats for head
template<int C>
__global__ __launch_bounds__(256) void bn_stats_kernel(const float* __restrict__ x, int n,
                                                       float* __restrict__ sums) {
    constexpr int RP = 256 / C;
    __shared__ float ls[256], ls2[256];
    int c = threadIdx.x % C;
    int sub = threadIdx.x / C;
    float s = 0.f, s2 = 0.f;
    for (int r = blockIdx.x * RP + sub; r < n; r += gridDim.x * RP) {
        float v = x[(size_t)r * C + c];
        s += v; s2 += v * v;
    }
    ls[threadIdx.x] = s; ls2[threadIdx.x] = s2;
    __syncthreads();
    if (sub == 0) {
#pragma unroll
        for (int k = 1; k < RP; ++k) { s += ls[k * C + c]; s2 += ls2[k * C + c]; }
        atomicAdd(&sums[c], s);
        atomicAdd(&sums[C + c], s2);
    }
}

// ---------------- Host orchestration ----------------

static inline size_t alignup(size_t x) { return (x + 255) & ~(size_t)255; }

extern "C" void kernel_launch(void* const* d_in, const int* in_sizes, int n_in,
                              void* d_out, int out_size, void* d_ws, size_t ws_size,
                              hipStream_t stream) {
    const float* xc  = (const float*)d_in[0];
    const float* xs  = (const float*)d_in[1];
    const int*   eic = (const int*)d_in[2];
    const int*   eis = (const int*)d_in[3];
    const int*   batch = (const int*)d_in[4];
    const float* W1c = (const float*)d_in[5];
    const float* g1c = (const float*)d_in[7];
    const float* be1c = (const float*)d_in[8];
    const float* W2c = (const float*)d_in[9];
    const float* g2c = (const float*)d_in[11];
    const float* be2c = (const float*)d_in[12];
    const float* W1s = (const float*)d_in[13];
    const float* g1s = (const float*)d_in[15];
    const float* be1s = (const float*)d_in[16];
    const float* W2s = (const float*)d_in[17];
    const float* g2s = (const float*)d_in[19];
    const float* be2s = (const float*)d_in[20];
    const float* Wf1 = (const float*)d_in[21];
    const float* gf1 = (const float*)d_in[23];
    const float* bef1 = (const float*)d_in[24];
    const float* Wf2 = (const float*)d_in[25];
    const float* bf2 = (const float*)d_in[26];
    float* out = (float*)d_out;

    char* ws = (char*)d_ws;
    size_t off = 0;
    auto alloc = [&](size_t bytes) { char* p = ws + off; off += alignup(bytes); return p; };

    int*   cnt      = (int*)alloc(2 * NN * 4);
    int*   row_ptr  = (int*)alloc(2 * (NN + 1) * 4);
    int*   cursor   = (int*)alloc(2 * NN * 4);
    int*   blk      = (int*)alloc(2 * NBLK * 4);
    int2*  perm     = (int2*)alloc(((size_t)2 * NE + 64) * 8);
    float* aggx     = (float*)alloc((size_t)2 * NN * 64 * 4);
    float* h1buf    = (float*)alloc((size_t)2 * NN * 128 * 4);
    float* h2buf    = (float*)alloc((size_t)2 * NN * 64 * 4);
    float* sums     = (float*)alloc((size_t)2 * SLOTS * 2 * 128 * 4);  // 32 KB
    float* hsums    = (float*)alloc(128 * 4);
    float* bnscale  = (float*)alloc(2 * 128 * 4);
    float* bnshift  = (float*)alloc(2 * 128 * 4);
    float* Hmean    = (float*)alloc((size_t)NG * 128 * 4);
    float* T        = (float*)alloc((size_t)NG * 64 * 4);

    const float invN = 1.0f / (float)NN;
    const dim3 eg((NE + 255) / 256, 2);
    const size_t sumsBytes = (size_t)2 * SLOTS * 2 * 128 * 4;
    const int nTiles = (NN + 63) / 64;   // 782

    // ---- CSR build for both branches ----
    hipMemsetAsync(cnt, 0, 2 * NN * 4, stream);
    count2_kernel<<<eg, 256, 0, stream>>>(eic + NE, eis + NE, cnt, NE);
    scan_pass1<<<dim3(NBLK, 2), 256, 0, stream>>>(cnt, blk, NN);
    scan_pass2<<<dim3(NBLK, 2), 256, 0, stream>>>(cnt, blk, row_ptr, cursor, NN);
    scatter2_kernel<<<eg, 256, 0, stream>>>(eic, eic + NE, eis, eis + NE,
                                            cnt, cursor, perm, NE);

    // ---- Layer 1: aggregate raw x (64ch), then GEMM 64->128 with fused BN stats ----
    agg2_kernel<false><<<dim3((NN + 3) / 4, 2), 256, 0, stream>>>(
        xc, xs, row_ptr, perm, cnt, aggx, nullptr, NN);
    hipMemsetAsync(sums, 0, sumsBytes, stream);
    gemm1_tile<true><<<dim3(nTiles, 2), 256, 0, stream>>>(
        aggx, aggx + (size_t)NN * 64, W1c, W1s,
        h1buf, h1buf + (size_t)NN * 128, sums, NN);
    bn_finalize2_kernel<<<dim3(1, 2), 128, 0, stream>>>(sums, 128, invN,
                                                        g1c, g1s, be1c, be1s, bnscale, bnshift);

    // ---- Layer 2: BN+ReLU fused into GEMM load, 128->64, then aggregate w/ fused stats ----
    gemm2_tile<<<dim3(nTiles, 2), 256, 0, stream>>>(
        h1buf, h1buf + (size_t)NN * 128, W2c, W2s, bnscale, bnshift,
        h2buf, h2buf + (size_t)NN * 64, NN);
    hipMemsetAsync(sums, 0, sumsBytes, stream);
    agg2_kernel<true><<<dim3((NN + 3) / 4, 2), 256, 0, stream>>>(
        h2buf, h2buf + (size_t)NN * 64, row_ptr, perm, cnt, aggx, sums, NN);
    bn_finalize2_kernel<<<dim3(1, 2), 64, 0, stream>>>(sums, 64, invN,
                                                       g2c, g2s, be2c, be2s, bnscale, bnshift);

    // ---- Pool (BN+ReLU fused) ----
    pool2_kernel<<<dim3(NG, 2), 64, 0, stream>>>(aggx, bnscale, bnshift, batch, Hmean, NN);

    // ---- Head ----
    head_gemm1_kernel<<<NG, 64, 0, stream>>>(Hmean, Wf1, T);
    hipMemsetAsync(hsums, 0, 128 * 4, stream);
    bn_stats_kernel<64><<<32, 256, 0, stream>>>(T, NG, hsums);
    bn_finalize_kernel<<<1, 64, 0, stream>>>(hsums, 64, 1.0f / (float)NG, gf1, bef1,
                                             bnscale, bnshift);
    head_final_kernel<<<NG, 64, 0, stream>>>(T, bnscale, bnshift, Wf2, bf2, out);
}

// Round 8
// 482.891 us; speedup vs baseline: 1.3288x; 1.0804x over previous
//
#include <hip/hip_runtime.h>
#include <hip/hip_bf16.h>
#include <cstdint>
#include <cstddef>

#define NN 50000
#define NE 600000
#define NG 2000
#define SCAN_TILE 1024
#define NBLK ((NN + SCAN_TILE - 1) / SCAN_TILE)
#define SLOTS 16

__device__ __forceinline__ unsigned short f2bf(float f) {
    uint32_t u = __float_as_uint(f);
    uint32_t r = (u + 0x7FFFu + ((u >> 16) & 1u)) >> 16;
    return (unsigned short)r;
}
__device__ __forceinline__ float bf2f(unsigned short h) {
    return __uint_as_float(((uint32_t)h) << 16);
}

// ---------------- CSR build (batched over 2 branches via blockIdx.y) ----------------

__global__ void count2_kernel(const int* __restrict__ d0, const int* __restrict__ d1,
                              int* __restrict__ cnt, int nE) {
    int b = blockIdx.y;
    const int* dst = b ? d1 : d0;
    int e = blockIdx.x * blockDim.x + threadIdx.x;
    if (e < nE) atomicAdd(&cnt[b * NN + dst[e]], 1);
}

__global__ __launch_bounds__(256) void scan_pass1(const int* __restrict__ cnt,
                                                  int* __restrict__ blk, int n) {
    __shared__ int sm[256];
    const int* cb = cnt + blockIdx.y * NN;
    int* bb = blk + blockIdx.y * NBLK;
    int t = threadIdx.x;
    int base = blockIdx.x * SCAN_TILE + t * 4;
    int s = 0;
#pragma unroll
    for (int j = 0; j < 4; ++j) { int i = base + j; if (i < n) s += cb[i]; }
    sm[t] = s;
    __syncthreads();
    for (int off = 128; off > 0; off >>= 1) {
        if (t < off) sm[t] += sm[t + off];
        __syncthreads();
    }
    if (t == 0) bb[blockIdx.x] = sm[0];
}

__global__ __launch_bounds__(256) void scan_pass2(const int* __restrict__ cnt,
                                                  const int* __restrict__ blk,
                                                  int* __restrict__ row_ptr,
                                                  int* __restrict__ cursor, int n) {
    __shared__ int sm[256];
    __shared__ int sbase;
    const int* cb = cnt + blockIdx.y * NN;
    const int* bb = blk + blockIdx.y * NBLK;
    int* rp = row_ptr + blockIdx.y * (NN + 1);
    int* cu = cursor + blockIdx.y * NN;
    int t = threadIdx.x;
    int b = 0;
    for (int i = t; i < blockIdx.x; i += 256) b += bb[i];
    sm[t] = b;
    __syncthreads();
    for (int off = 128; off > 0; off >>= 1) {
        if (t < off) sm[t] += sm[t + off];
        __syncthreads();
    }
    if (t == 0) sbase = sm[0];
    __syncthreads();
    int base = sbase;
    __syncthreads();

    int i0 = blockIdx.x * SCAN_TILE + t * 4;
    int v[4];
    int s = 0;
#pragma unroll
    for (int j = 0; j < 4; ++j) { int i = i0 + j; v[j] = (i < n) ? cb[i] : 0; s += v[j]; }
    sm[t] = s;
    __syncthreads();
    for (int off = 1; off < 256; off <<= 1) {
        int tmp = (t >= off) ? sm[t - off] : 0;
        __syncthreads();
        sm[t] += tmp;
        __syncthreads();
    }
    int run = base + sm[t] - s;
#pragma unroll
    for (int j = 0; j < 4; ++j) {
        int i = i0 + j;
        if (i < n) {
            rp[i] = run;
            cu[i] = run;
            run += v[j];
            if (i == n - 1) rp[n] = run;
        }
    }
}

// packed CSR entry: (w_bf16 << 16) | src  (src < 50000 < 2^16) -> one 4B store per edge
__global__ void scatter2_kernel(const int* __restrict__ s0, const int* __restrict__ d0,
                                const int* __restrict__ s1, const int* __restrict__ d1,
                                const int* __restrict__ cnt, int* __restrict__ cursor,
                                uint32_t* __restrict__ perm, int nE) {
    int b = blockIdx.y;
    const int* src = b ? s1 : s0;
    const int* dst = b ? d1 : d0;
    int e = blockIdx.x * blockDim.x + threadIdx.x;
    if (e >= nE) return;
    int d = dst[e];
    int p = atomicAdd(&cursor[b * NN + d], 1);
    int s = src[e];
    float w = rsqrtf((float)cnt[b * NN + s] + 1.0f);
    perm[(size_t)b * NE + p] = ((uint32_t)f2bf(w) << 16) | (uint32_t)s;
}

// ---------------- fp32 -> bf16 conversion (x inputs) ----------------
__global__ __launch_bounds__(256) void conv_bf16_kernel(const float* __restrict__ x0,
                                                        const float* __restrict__ x1,
                                                        unsigned short* __restrict__ out) {
    int b = blockIdx.y;
    const float* x = b ? x1 : x0;
    unsigned short* o = out + (size_t)b * NN * 64;
    int i = (blockIdx.x * 256 + threadIdx.x) * 4;
    if (i + 3 < NN * 64) {
        float4 v = *(const float4*)&x[i];
        ushort4 r = make_ushort4(f2bf(v.x), f2bf(v.y), f2bf(v.z), f2bf(v.w));
        *(ushort4*)&o[i] = r;
    }
}

// ---------------- GEMM1: Y[n,128] = X[n,64] @ W[64,128], 64-row tile ----------------
template<bool STATS>
__global__ __launch_bounds__(256) void gemm1_tile(const float* __restrict__ X0,
                                                  const float* __restrict__ X1,
                                                  const float* __restrict__ W0,
                                                  const float* __restrict__ W1,
                                                  float* __restrict__ Y0,
                                                  float* __restrict__ Y1,
                                                  float* __restrict__ sums, int nRows) {
    __shared__ float Ws[64 * 128];   // 32 KB
    __shared__ float Xs[64 * 68];    // 17.4 KB, [k][row], pad 68
    __shared__ float ls[128], ls2[128];
    const int b = blockIdx.y;
    const float* __restrict__ X = b ? X1 : X0;
    const float* __restrict__ W = b ? W1 : W0;
    float* __restrict__ Y = b ? Y1 : Y0;
    const int tid = threadIdx.x;
    const int row0 = blockIdx.x * 64;

    for (int i = tid; i < 64 * 128; i += 256) Ws[i] = W[i];
    for (int i = tid; i < 64 * 64; i += 256) {
        int row = i >> 6, k = i & 63;
        int gr = row0 + row;
        Xs[k * 68 + row] = (gr < nRows) ? X[(size_t)gr * 64 + k] : 0.f;
    }
    if (STATS) {
        for (int i = tid; i < 128; i += 256) { ls[i] = 0.f; ls2[i] = 0.f; }
    }
    __syncthreads();

    const int cg = tid & 31;
    const int rg = tid >> 5;
    float acc[8][4];
#pragma unroll
    for (int r = 0; r < 8; ++r)
#pragma unroll
        for (int j = 0; j < 4; ++j) acc[r][j] = 0.f;

#pragma unroll 4
    for (int k = 0; k < 64; ++k) {
        float4 b4 = *(const float4*)&Ws[k * 128 + cg * 4];
        float4 a0 = *(const float4*)&Xs[k * 68 + rg * 8];
        float4 a1 = *(const float4*)&Xs[k * 68 + rg * 8 + 4];
        float a[8] = {a0.x, a0.y, a0.z, a0.w, a1.x, a1.y, a1.z, a1.w};
#pragma unroll
        for (int r = 0; r < 8; ++r) {
            acc[r][0] = fmaf(a[r], b4.x, acc[r][0]);
            acc[r][1] = fmaf(a[r], b4.y, acc[r][1]);
            acc[r][2] = fmaf(a[r], b4.z, acc[r][2]);
            acc[r][3] = fmaf(a[r], b4.w, acc[r][3]);
        }
    }
#pragma unroll
    for (int r = 0; r < 8; ++r) {
        int gr = row0 + rg * 8 + r;
        if (gr < nRows) {
            float4 st = make_float4(acc[r][0], acc[r][1], acc[r][2], acc[r][3]);
            *(float4*)&Y[(size_t)gr * 128 + cg * 4] = st;
        }
    }
    if (STATS) {
#pragma unroll
        for (int j = 0; j < 4; ++j) {
            float sj = 0.f, s2j = 0.f;
#pragma unroll
            for (int r = 0; r < 8; ++r) { float v = acc[r][j]; sj += v; s2j = fmaf(v, v, s2j); }
            atomicAdd(&ls[cg * 4 + j], sj);
            atomicAdd(&ls2[cg * 4 + j], s2j);
        }
        __syncthreads();
        int slot = blockIdx.x & (SLOTS - 1);
        float* sb = sums + (size_t)(b * SLOTS + slot) * 256;
        if (tid < 128) {
            atomicAdd(&sb[tid], ls[tid]);
            atomicAdd(&sb[128 + tid], ls2[tid]);
        }
    }
}

// ---------------- GEMM2: Ybf16[n,64] = BNReLU(X[n,128]) @ W[128,64], 64x64 tile ----------------
__global__ __launch_bounds__(256) void gemm2_tile(const float* __restrict__ X0,
                                                  const float* __restrict__ X1,
                                                  const float* __restrict__ W0,
                                                  const float* __restrict__ W1,
                                                  const float* __restrict__ scale,
                                                  const float* __restrict__ shift,
                                                  unsigned short* __restrict__ Y0,
                                                  unsigned short* __restrict__ Y1, int nRows) {
    __shared__ float Ws[128 * 64];   // 32 KB
    __shared__ float Xs[64 * 68];    // 17.4 KB chunk: [kk][row]
    const int b = blockIdx.y;
    const float* __restrict__ X = b ? X1 : X0;
    const float* __restrict__ W = b ? W1 : W0;
    const float* sc = scale + b * 128;
    const float* sh = shift + b * 128;
    unsigned short* __restrict__ Y = b ? Y1 : Y0;
    const int tid = threadIdx.x;
    const int row0 = blockIdx.x * 64;

    for (int i = tid; i < 128 * 64; i += 256) Ws[i] = W[i];

    const int cg = tid & 15;
    const int rg = tid >> 4;
    float acc[4][4];
#pragma unroll
    for (int r = 0; r < 4; ++r)
#pragma unroll
        for (int j = 0; j < 4; ++j) acc[r][j] = 0.f;

    for (int ch = 0; ch < 2; ++ch) {
        __syncthreads();
        for (int i = tid; i < 64 * 64; i += 256) {
            int row = i >> 6, kk = i & 63;
            int kg = ch * 64 + kk;
            int gr = row0 + row;
            float v = 0.f;
            if (gr < nRows) v = fmaxf(fmaf(X[(size_t)gr * 128 + kg], sc[kg], sh[kg]), 0.f);
            Xs[kk * 68 + row] = v;
        }
        __syncthreads();
#pragma unroll 4
        for (int kk = 0; kk < 64; ++kk) {
            float4 b4 = *(const float4*)&Ws[(ch * 64 + kk) * 64 + cg * 4];
            float4 a4 = *(const float4*)&Xs[kk * 68 + rg * 4];
            float a[4] = {a4.x, a4.y, a4.z, a4.w};
#pragma unroll
            for (int r = 0; r < 4; ++r) {
                acc[r][0] = fmaf(a[r], b4.x, acc[r][0]);
                acc[r][1] = fmaf(a[r], b4.y, acc[r][1]);
                acc[r][2] = fmaf(a[r], b4.z, acc[r][2]);
                acc[r][3] = fmaf(a[r], b4.w, acc[r][3]);
            }
        }
    }
#pragma unroll
    for (int r = 0; r < 4; ++r) {
        int gr = row0 + rg * 4 + r;
        if (gr < nRows) {
            ushort4 st = make_ushort4(f2bf(acc[r][0]), f2bf(acc[r][1]),
                                      f2bf(acc[r][2]), f2bf(acc[r][3]));
            *(ushort4*)&Y[(size_t)gr * 64 + cg * 4] = st;
        }
    }
}

// ---------------- Batched aggregation (C=64, bf16 h): one wave per dst node, unroll-8 ----------------
template<bool STATS>
__global__ __launch_bounds__(256) void agg2_kernel(const unsigned short* __restrict__ hall,
                                                   const int* __restrict__ row_ptr,
                                                   const uint32_t* __restrict__ perm,
                                                   const int* __restrict__ cnt,
                                                   float* __restrict__ out,
                                                   float* __restrict__ sums, int nNodes) {
    const int b = blockIdx.y;
    const unsigned short* __restrict__ h = hall + (size_t)b * NN * 64;
    const int* rp = row_ptr + b * (NN + 1);
    const uint32_t* pe = perm + (size_t)b * NE;
    const int* cc = cnt + b * NN;
    float* ob = out + (size_t)b * nNodes * 64;

    const int wave = blockIdx.x * 4 + (threadIdx.x >> 6);
    const int lane = threadIdx.x & 63;
    float fin = 0.f;
    const bool active = wave < nNodes;
    if (active) {
        const int d = wave;
        const float di = rsqrtf((float)cc[d] + 1.0f);
        const int p0 = rp[d], p1 = rp[d + 1];
        float a = 0.f;
        for (int p = p0; p < p1; p += 8) {
            int idx[8]; float w[8];
#pragma unroll
            for (int k = 0; k < 8; ++k) {
                bool vld = (p + k) < p1;
                int pk = vld ? (p + k) : p;   // dup of first slot: same cache line, w=0
                uint32_t en = pe[pk];
                idx[k] = (int)(en & 0xFFFFu);
                w[k] = vld ? bf2f((unsigned short)(en >> 16)) : 0.f;
            }
            float v[8];
#pragma unroll
            for (int k = 0; k < 8; ++k) v[k] = bf2f(h[(size_t)idx[k] * 64 + lane]);
#pragma unroll
            for (int k = 0; k < 8; ++k) a = fmaf(w[k], v[k], a);
        }
        float hd = bf2f(h[(size_t)d * 64 + lane]);
        fin = di * fmaf(di, hd, a);   // di*(sum + di*h_d)
        ob[(size_t)d * 64 + lane] = fin;
    }
    if constexpr (STATS) {
        __shared__ float ls[256], ls2[256];
        ls[threadIdx.x] = fin;
        ls2[threadIdx.x] = fin * fin;
        __syncthreads();
        if (threadIdx.x < 64) {
            float s  = ls[threadIdx.x] + ls[threadIdx.x + 64] + ls[threadIdx.x + 128] + ls[threadIdx.x + 192];
            float s2 = ls2[threadIdx.x] + ls2[threadIdx.x + 64] + ls2[threadIdx.x + 128] + ls2[threadIdx.x + 192];
            int slot = blockIdx.x & (SLOTS - 1);
            float* sb = sums + ((size_t)(b * SLOTS + slot) * 2) * 64;
            atomicAdd(&sb[threadIdx.x], s);
            atomicAdd(&sb[64 + threadIdx.x], s2);
        }
    }
}

// ---------------- BN finalize (slot-striped sums) ----------------
__global__ void bn_finalize2_kernel(const float* __restrict__ sums, int C, float invN,
                                    const float* __restrict__ g0, const float* __restrict__ g1,
                                    const float* __restrict__ b0, const float* __restrict__ b1,
                                    float* __restrict__ scale, float* __restrict__ shift) {
    int b = blockIdx.y;
    int c = threadIdx.x;
    if (c >= C) return;
    float s = 0.f, s2 = 0.f;
    for (int k = 0; k < SLOTS; ++k) {
        const float* sb = sums + ((size_t)(b * SLOTS + k) * 2) * C;
        s += sb[c];
        s2 += sb[C + c];
    }
    const float* gamma = b ? g1 : g0;
    const float* beta = b ? b1 : b0;
    float m = s * invN;
    float var = s2 * invN - m * m;
    float sc = gamma[c] * rsqrtf(var + 1e-5f);
    scale[b * C + c] = sc;
    shift[b * C + c] = beta[c] - m * sc;
}

// single (for head)
__global__ void bn_finalize_kernel(const float* __restrict__ sums, int C, float invN,
                                   const float* __restrict__ gamma, const float* __restrict__ beta,
                                   float* __restrict__ scale, float* __restrict__ shift) {
    int c = blockIdx.x * blockDim.x + threadIdx.x;
    if (c >= C) return;
    float m = sums[c] * invN;
    float var = sums[C + c] * invN - m * m;
    float sc = gamma[c] * rsqrtf(var + 1e-5f);
    scale[c] = sc;
    shift[c] = beta[c] - m * sc;
}

// ---------------- Mean pool per graph (batched; batch sorted; binary search) ----------------
__global__ __launch_bounds__(64) void pool2_kernel(const float* __restrict__ x,
                                                   const float* __restrict__ scale,
                                                   const float* __restrict__ shift,
                                                   const int* __restrict__ batch,
                                                   float* __restrict__ Hmean, int n) {
    int b = blockIdx.y;
    const float* xb = x + (size_t)b * NN * 64;
    int g = blockIdx.x;
    int c = threadIdx.x;
    int lo = 0, hi = n;
    while (lo < hi) { int mid = (lo + hi) >> 1; if (batch[mid] < g) lo = mid + 1; else hi = mid; }
    int start = lo;
    hi = n;
    while (lo < hi) { int mid = (lo + hi) >> 1; if (batch[mid] <= g) lo = mid + 1; else hi = mid; }
    int end = lo;
    float s = 0.f;
    float sc = scale[b * 64 + c], sh = shift[b * 64 + c];
    for (int r = start; r < end; ++r)
        s += fmaxf(fmaf(xb[(size_t)r * 64 + c], sc, sh), 0.f);
    float cf = (float)(end - start);
    Hmean[(size_t)g * 128 + b * 64 + c] = s / fmaxf(cf, 1.f);
}

// ---------------- Head ----------------
__global__ __launch_bounds__(64) void head_gemm1_kernel(const float* __restrict__ H,
                                                        const float* __restrict__ Wf1,
                                                        float* __restrict__ T) {
    __shared__ float row[128];
    int g = blockIdx.x;
    int c = threadIdx.x;
    row[c] = H[(size_t)g * 128 + c];
    row[c + 64] = H[(size_t)g * 128 + 64 + c];
    __syncthreads();
    float acc = 0.f;
#pragma unroll 8
    for (int k = 0; k < 128; ++k) acc = fmaf(row[k], Wf1[k * 64 + c], acc);
    T[(size_t)g * 64 + c] = acc;
}

__global__ __launch_bounds__(64) void head_final_kernel(const float* __restrict__ T,
                                                        const float* __restrict__ scale,
                                                        const float* __restrict__ shift,
                                                        const float* __restrict__ Wf2,
                                                        const float* __restrict__ bf2,
                                                        float* __restrict__ out) {
    int g = blockIdx.x;
    int c = threadIdx.x;
    float v = fmaxf(fmaf(T[(size_t)g * 64 + c], scale[c], shift[c]), 0.f) * Wf2[c];
#pragma unroll
    for (int off = 32; off > 0; off >>= 1) v += __shfl_down(v, off, 64);
    if (c == 0) out[g] = v + bf2[0];
}

// single-branch bn_stats for head
template<int C>
__global__ __launch_bounds__(256) void bn_stats_kernel(const float* __restrict__ x, int n,
                                                       float* __restrict__ sums) {
    constexpr int RP = 256 / C;
    __shared__ float ls[256], ls2[256];
    int c = threadIdx.x % C;
    int sub = threadIdx.x / C;
    float s = 0.f, s2 = 0.f;
    for (int r = blockIdx.x * RP + sub; r < n; r += gridDim.x * RP) {
        float v = x[(size_t)r * C + c];
        s += v; s2 += v * v;
    }
    ls[threadIdx.x] = s; ls2[threadIdx.x] = s2;
    __syncthreads();
    if (sub == 0) {
#pragma unroll
        for (int k = 1; k < RP; ++k) { s += ls[k * C + c]; s2 += ls2[k * C + c]; }
        atomicAdd(&sums[c], s);
        atomicAdd(&sums[C + c], s2);
    }
}

// ---------------- Host orchestration ----------------

static inline size_t alignup(size_t x) { return (x + 255) & ~(size_t)255; }

extern "C" void kernel_launch(void* const* d_in, const int* in_sizes, int n_in,
                              void* d_out, int out_size, void* d_ws, size_t ws_size,
                              hipStream_t stream) {
    const float* xc  = (const float*)d_in[0];
    const float* xs  = (const float*)d_in[1];
    const int*   eic = (const int*)d_in[2];
    const int*   eis = (const int*)d_in[3];
    const int*   batch = (const int*)d_in[4];
    const float* W1c = (const float*)d_in[5];
    const float* g1c = (const float*)d_in[7];
    const float* be1c = (const float*)d_in[8];
    const float* W2c = (const float*)d_in[9];
    const float* g2c = (const float*)d_in[11];
    const float* be2c = (const float*)d_in[12];
    const float* W1s = (const float*)d_in[13];
    const float* g1s = (const float*)d_in[15];
    const float* be1s = (const float*)d_in[16];
    const float* W2s = (const float*)d_in[17];
    const float* g2s = (const float*)d_in[19];
    const float* be2s = (const float*)d_in[20];
    const float* Wf1 = (const float*)d_in[21];
    const float* gf1 = (const float*)d_in[23];
    const float* bef1 = (const float*)d_in[24];
    const float* Wf2 = (const float*)d_in[25];
    const float* bf2 = (const float*)d_in[26];
    float* out = (float*)d_out;

    char* ws = (char*)d_ws;
    size_t off = 0;
    auto alloc = [&](size_t bytes) { char* p = ws + off; off += alignup(bytes); return p; };

    int*      cnt      = (int*)alloc(2 * NN * 4);
    int*      row_ptr  = (int*)alloc(2 * (NN + 1) * 4);
    int*      cursor   = (int*)alloc(2 * NN * 4);
    int*      blk      = (int*)alloc(2 * NBLK * 4);
    uint32_t* perm     = (uint32_t*)alloc(((size_t)2 * NE + 64) * 4);
    unsigned short* xbf  = (unsigned short*)alloc((size_t)2 * NN * 64 * 2);
    unsigned short* h2bf = (unsigned short*)alloc((size_t)2 * NN * 64 * 2);
    float*    aggx     = (float*)alloc((size_t)2 * NN * 64 * 4);
    float*    h1buf    = (float*)alloc((size_t)2 * NN * 128 * 4);
    float*    sums     = (float*)alloc((size_t)2 * SLOTS * 2 * 128 * 4);
    float*    hsums    = (float*)alloc(128 * 4);
    float*    bnscale  = (float*)alloc(2 * 128 * 4);
    float*    bnshift  = (float*)alloc(2 * 128 * 4);
    float*    Hmean    = (float*)alloc((size_t)NG * 128 * 4);
    float*    T        = (float*)alloc((size_t)NG * 64 * 4);

    const float invN = 1.0f / (float)NN;
    const dim3 eg((NE + 255) / 256, 2);
    const size_t sumsBytes = (size_t)2 * SLOTS * 2 * 128 * 4;
    const int nTiles = (NN + 63) / 64;   // 782

    // ---- x -> bf16 (for layer-1 gather) ----
    conv_bf16_kernel<<<dim3((NN * 64 / 4 + 255) / 256, 2), 256, 0, stream>>>(xc, xs, xbf);

    // ---- CSR build for both branches ----
    hipMemsetAsync(cnt, 0, 2 * NN * 4, stream);
    count2_kernel<<<eg, 256, 0, stream>>>(eic + NE, eis + NE, cnt, NE);
    scan_pass1<<<dim3(NBLK, 2), 256, 0, stream>>>(cnt, blk, NN);
    scan_pass2<<<dim3(NBLK, 2), 256, 0, stream>>>(cnt, blk, row_ptr, cursor, NN);
    scatter2_kernel<<<eg, 256, 0, stream>>>(eic, eic + NE, eis, eis + NE,
                                            cnt, cursor, perm, NE);

    // ---- Layer 1: aggregate bf16 x (64ch), then GEMM 64->128 with fused BN stats ----
    agg2_kernel<false><<<dim3((NN + 3) / 4, 2), 256, 0, stream>>>(
        xbf, row_ptr, perm, cnt, aggx, nullptr, NN);
    hipMemsetAsync(sums, 0, sumsBytes, stream);
    gemm1_tile<true><<<dim3(nTiles, 2), 256, 0, stream>>>(
        aggx, aggx + (size_t)NN * 64, W1c, W1s,
        h1buf, h1buf + (size_t)NN * 128, sums, NN);
    bn_finalize2_kernel<<<dim3(1, 2), 128, 0, stream>>>(sums, 128, invN,
                                                        g1c, g1s, be1c, be1s, bnscale, bnshift);

    // ---- Layer 2: BN+ReLU fused into GEMM load, 128->64 (bf16 out), then aggregate ----
    gemm2_tile<<<dim3(nTiles, 2), 256, 0, stream>>>(
        h1buf, h1buf + (size_t)NN * 128, W2c, W2s, bnscale, bnshift,
        h2bf, h2bf + (size_t)NN * 64, NN);
    hipMemsetAsync(sums, 0, sumsBytes, stream);
    agg2_kernel<true><<<dim3((NN + 3) / 4, 2), 256, 0, stream>>>(
        h2bf, row_ptr, perm, cnt, aggx, sums, NN);
    bn_finalize2_kernel<<<dim3(1, 2), 64, 0, stream>>>(sums, 64, invN,
                                                       g2c, g2s, be2c, be2s, bnscale, bnshift);

    // ---- Pool (BN+ReLU fused) ----
    pool2_kernel<<<dim3(NG, 2), 64, 0, stream>>>(aggx, bnscale, bnshift, batch, Hmean, NN);

    // ---- Head ----
    head_gemm1_kernel<<<NG, 64, 0, stream>>>(Hmean, Wf1, T);
    hipMemsetAsync(hsums, 0, 128 * 4, stream);
    bn_stats_kernel<64><<<32, 256, 0, stream>>>(T, NG, hsums);
    bn_finalize_kernel<<<1, 64, 0, stream>>>(hsums, 64, 1.0f / (float)NG, gf1, bef1,
                                             bnscale, bnshift);
    head_final_kernel<<<NG, 64, 0, stream>>>(T, bnscale, bnshift, Wf2, bf2, out);
}